// Round 7
// baseline (251.429 us; speedup 1.0000x reference)
//
#include <hip/hip_runtime.h>

#define BINS  30
#define NROWS 8192
#define NCOLS 2048
#define COLS_PER_BLK 256                 // grid.x = 8
#define ROWS_PER_BLK 128                 // grid.y = 64
#define YSLICES 64
#define CELLS   (BINS * NCOLS)           // 61440

#define FIXED_SCALE 16384.0f             // 2^14 fixed point for bce
#define CNT_SHIFT   24                   // count bits [24:31], sum in [0:24)
#define SUM_MASK    ((1u << CNT_SHIFT) - 1)

// ws layout (bytes) — unchanged:
//   part : u32[YSLICES][BINS][NCOLS]   (15.7 MB)
//   blockPart: float[8]
//   ctr  : u32
#define WS_PART  0
#define WS_BPART (YSLICES * BINS * NCOLS * 4)
#define WS_CTR   (WS_BPART + 8 * 4)

// ---------------------------------------------------------------------------
// Kernel A (FROZEN since R3): direct column ownership. ~50 us wall,
// invariant across 4 structures — this round ablates it (see diagnostics).
// ---------------------------------------------------------------------------
__global__ __launch_bounds__(256, 5) void k_main(
    const float* __restrict__ preds, const int* __restrict__ targets,
    unsigned int* __restrict__ part, unsigned int* __restrict__ ctr)
{
    __shared__ unsigned int H[BINS * COLS_PER_BLK];   // 30720 B
    const int t = threadIdx.x;
    if (blockIdx.x == 0 && blockIdx.y == 0 && t == 0) atomicExch(ctr, 0u);
    #pragma unroll
    for (int i = 0; i < BINS; ++i) H[i * COLS_PER_BLK + t] = 0u;
    __syncthreads();

    const int col = blockIdx.x * COLS_PER_BLK + t;
    const int r0  = blockIdx.y * ROWS_PER_BLK;
    const float* P = preds   + (size_t)r0 * NCOLS + col;
    const int*   T = targets + (size_t)r0 * NCOLS + col;

    float pc[8]; int tc[8];
    #pragma unroll
    for (int r = 0; r < 8; ++r) { pc[r] = P[r * NCOLS]; tc[r] = T[r * NCOLS]; }

    #pragma unroll 1
    for (int batch = 0; batch < ROWS_PER_BLK / 8; ++batch) {
        float pn[8]; int tn[8];
        if (batch < ROWS_PER_BLK / 8 - 1) {
            P += 8 * NCOLS; T += 8 * NCOLS;
            #pragma unroll
            for (int r = 0; r < 8; ++r) { pn[r] = P[r * NCOLS]; tn[r] = T[r * NCOLS]; }
        }
        __builtin_amdgcn_sched_barrier(0);

        #pragma unroll
        for (int r = 0; r < 8; ++r) {
            float p  = pc[r];
            float pp = tc[r] ? -p : p;
            float e  = __expf(-fabsf(pp));
            float d  = 1.0f + e;
            float r1 = __builtin_amdgcn_rcpf(d);
            float g  = (pp >= 0.0f) ? r1 : e * r1;
            int   b  = (int)(g * 30.0f);
            b = b > (BINS - 1) ? (BINS - 1) : b;
            float bce = fmaxf(pp, 0.0f) + __logf(d);
            unsigned int pk = (1u << CNT_SHIFT)
                | (unsigned int)(bce * FIXED_SCALE + 0.5f);
            H[b * COLS_PER_BLK + t] += pk;
        }
        #pragma unroll
        for (int r = 0; r < 8; ++r) { pc[r] = pn[r]; tc[r] = tn[r]; }
    }
    __syncthreads();

    const size_t outBase = (size_t)blockIdx.y * BINS * NCOLS
                         + (size_t)blockIdx.x * COLS_PER_BLK;
    for (int i = t; i < BINS * COLS_PER_BLK; i += 256)
        part[outBase + (size_t)(i >> 8) * NCOLS + (i & 255)] = H[i];
}

// ---------------------------------------------------------------------------
// Kernel B (R5): parallel y-slice reduction, in-place into part. Unchanged.
// ---------------------------------------------------------------------------
__global__ __launch_bounds__(256) void k_reduce16(
    unsigned int* __restrict__ part)
{
    const int gid   = blockIdx.x * 256 + threadIdx.x;
    const int chunk = gid / CELLS;
    const int cell  = gid % CELLS;
    unsigned int* Pp = part + (size_t)(chunk * 16) * CELLS + cell;

    unsigned int c = 0u, s = 0u;
    #pragma unroll
    for (int y = 0; y < 16; ++y) {
        const unsigned int v = Pp[(size_t)y * CELLS];
        c += v >> CNT_SHIFT;
        s += v & SUM_MASK;
    }
    Pp[0]     = c;
    Pp[CELLS] = s;
}

// ---------------------------------------------------------------------------
// Kernel C (R5): per-column contraction + deterministic finale. Unchanged.
// ---------------------------------------------------------------------------
__global__ __launch_bounds__(256) void k_tail(
    const unsigned int* __restrict__ part,
    const float* __restrict__ acc_sum,
    float* __restrict__ blockPart, unsigned int* __restrict__ ctr,
    float* __restrict__ out)
{
    __shared__ float wave_sums[4];
    const int t = threadIdx.x;
    const int c = blockIdx.x * 256 + t;

    float colsum = 0.0f;
    int n = 0;
    #pragma unroll
    for (int b = 0; b < BINS; ++b) {
        const int cell = b * NCOLS + c;
        unsigned int cu = part[(size_t) 0 * CELLS + cell]
                        + part[(size_t)16 * CELLS + cell]
                        + part[(size_t)32 * CELLS + cell]
                        + part[(size_t)48 * CELLS + cell];
        unsigned int su = part[(size_t) 1 * CELLS + cell]
                        + part[(size_t)17 * CELLS + cell]
                        + part[(size_t)33 * CELLS + cell]
                        + part[(size_t)49 * CELLS + cell];
        const float cnt = (float)cu;
        if (cnt >= 1.0f) {
            n += 1;
            float acc_new = 0.75f * acc_sum[cell] + 0.25f * cnt;
            colsum += ((float)su * (1.0f / FIXED_SCALE)) / acc_new;
        }
    }
    colsum /= (float)((n > 1 ? n : 1) * NCOLS);

    #pragma unroll
    for (int off = 32; off > 0; off >>= 1)
        colsum += __shfl_down(colsum, off, 64);
    if ((t & 63) == 0) wave_sums[t >> 6] = colsum;
    __syncthreads();

    if (t == 0) {
        const float s = wave_sums[0] + wave_sums[1] + wave_sums[2] + wave_sums[3];
        atomicExch(&blockPart[blockIdx.x], s);
        __threadfence();
        if (atomicAdd(ctr, 1u) == 7u) {
            __threadfence();
            double d = 0.0;
            #pragma unroll
            for (int i = 0; i < 8; ++i)
                d += (double)atomicAdd(&blockPart[i], 0.0f);
            out[0] = (float)d;
        }
    }
}

// ===========================================================================
// DIAGNOSTICS (R7) — dead-output ablation of k_main, run AFTER k_tail.
// Output of these kernels is never read; part is fully rewritten by k_main
// on the next replay iteration, so they cannot poison correctness.
// ===========================================================================

// D1: k_main's LOADS ONLY, x3 passes. Same grid, same 30KB LDS (occupancy
// replica: 5 blk/CU), same batch/prefetch structure, values pinned by asm
// keep-alives (no DCE). Read its dur_us directly from the dispatch table:
//   ~135-150 -> memory path IS the wall; ~60-75 -> memory path is fine.
__global__ __launch_bounds__(256, 5) void k_loadonly(
    const float* __restrict__ preds, const int* __restrict__ targets)
{
    __shared__ unsigned int Hd[BINS * COLS_PER_BLK];   // occupancy replica
    const int t = threadIdx.x;
    #pragma unroll
    for (int i = 0; i < BINS; ++i) Hd[i * COLS_PER_BLK + t] = 0u;
    __syncthreads();
    unsigned int keep = Hd[t];
    asm volatile("" :: "v"(keep));                     // pin LDS allocation

    const int col = blockIdx.x * COLS_PER_BLK + t;

    #pragma unroll 1
    for (int pass = 0; pass < 3; ++pass) {
        const float* P = preds   + (size_t)(blockIdx.y * ROWS_PER_BLK) * NCOLS + col;
        const int*   T = targets + (size_t)(blockIdx.y * ROWS_PER_BLK) * NCOLS + col;

        float pc[8]; int tc[8];
        #pragma unroll
        for (int r = 0; r < 8; ++r) { pc[r] = P[r * NCOLS]; tc[r] = T[r * NCOLS]; }

        #pragma unroll 1
        for (int batch = 0; batch < ROWS_PER_BLK / 8; ++batch) {
            float pn[8]; int tn[8];
            if (batch < ROWS_PER_BLK / 8 - 1) {
                P += 8 * NCOLS; T += 8 * NCOLS;
                #pragma unroll
                for (int r = 0; r < 8; ++r) { pn[r] = P[r * NCOLS]; tn[r] = T[r * NCOLS]; }
            }
            __builtin_amdgcn_sched_barrier(0);
            #pragma unroll
            for (int r = 0; r < 8; ++r) {
                asm volatile("" :: "v"(pc[r]), "v"(tc[r]));   // consume
            }
            #pragma unroll
            for (int r = 0; r < 8; ++r) { pc[r] = pn[r]; tc[r] = tn[r]; }
        }
    }
}

// D2: k_main's VALU/trans + LDS-RMW chain + flush, ZERO global loads
// (LCG-synthesized p,t with realistic bin distribution). Its dur is
// recovered from: dur_us - 180 - t(k_loadonly3x).
//   ~40-50 -> LDS-RMW serial chain is the wall; ~15-20 -> it is not.
__global__ __launch_bounds__(256, 5) void k_ldsmath(
    unsigned int* __restrict__ part)
{
    __shared__ unsigned int H[BINS * COLS_PER_BLK];
    const int t = threadIdx.x;
    #pragma unroll
    for (int i = 0; i < BINS; ++i) H[i * COLS_PER_BLK + t] = 0u;
    __syncthreads();

    unsigned int u = (blockIdx.x * 2048u + blockIdx.y * 256u + t) * 2654435761u
                   + 1013904223u;

    #pragma unroll 1
    for (int batch = 0; batch < ROWS_PER_BLK / 8; ++batch) {
        #pragma unroll
        for (int r = 0; r < 8; ++r) {
            u = u * 1664525u + 1013904223u;
            float p  = (float)(int)u * (4.0f / 2147483648.0f);   // [-4,4)
            float pp = (u & 1u) ? -p : p;
            float e  = __expf(-fabsf(pp));
            float d  = 1.0f + e;
            float r1 = __builtin_amdgcn_rcpf(d);
            float g  = (pp >= 0.0f) ? r1 : e * r1;
            int   b  = (int)(g * 30.0f);
            b = b > (BINS - 1) ? (BINS - 1) : b;
            float bce = fmaxf(pp, 0.0f) + __logf(d);
            unsigned int pk = (1u << CNT_SHIFT)
                | (unsigned int)(bce * FIXED_SCALE + 0.5f);
            H[b * COLS_PER_BLK + t] += pk;       // identical RMW chain
        }
    }
    __syncthreads();

    // flush (prevents DCE); part is dead here, rewritten next iteration
    const size_t outBase = (size_t)blockIdx.y * BINS * NCOLS
                         + (size_t)blockIdx.x * COLS_PER_BLK;
    for (int i = t; i < BINS * COLS_PER_BLK; i += 256)
        part[outBase + (size_t)(i >> 8) * NCOLS + (i & 255)] = H[i];
}

extern "C" void kernel_launch(void* const* d_in, const int* in_sizes, int n_in,
                              void* d_out, int out_size, void* d_ws, size_t ws_size,
                              hipStream_t stream)
{
    const float* preds   = (const float*)d_in[0];
    const int*   targets = (const int*)d_in[1];
    const float* acc_sum = (const float*)d_in[2];

    unsigned int* part = (unsigned int*)((char*)d_ws + WS_PART);
    float* blockPart   = (float*)((char*)d_ws + WS_BPART);
    unsigned int* ctr  = (unsigned int*)((char*)d_ws + WS_CTR);

    dim3 gA(NCOLS / COLS_PER_BLK, NROWS / ROWS_PER_BLK);   // (8, 64)
    k_main<<<gA, 256, 0, stream>>>(preds, targets, part, ctr);

    k_reduce16<<<(4 * CELLS) / 256, 256, 0, stream>>>(part);

    k_tail<<<NCOLS / 256, 256, 0, stream>>>(part, acc_sum, blockPart, ctr,
                                            (float*)d_out);

    // --- diagnostics (dead output, run after the answer is produced) ---
    k_loadonly<<<gA, 256, 0, stream>>>(preds, targets);
    k_ldsmath<<<gA, 256, 0, stream>>>(part);
}

// Round 8
// 184.343 us; speedup vs baseline: 1.3639x; 1.3639x over previous
//
#include <hip/hip_runtime.h>

#define BINS  30
#define NROWS 8192
#define NCOLS 2048
#define COLS_PER_BLK 64                  // R8: narrow blocks, grid.x = 32
#define ROWS_PER_BLK 128                 // grid.y = 64 (part layout unchanged)
#define ROW_SPLIT 4                      // 4 row-groups of 32 rows per block
#define YSLICES 64
#define CELLS   (BINS * NCOLS)           // 61440

#define FIXED_SCALE 16384.0f             // 2^14 fixed point for bce
#define CNT_SHIFT   24                   // count bits [24:31], sum in [0:24)
#define SUM_MASK    ((1u << CNT_SHIFT) - 1)

// ws layout (bytes) — unchanged:
//   part : u32[YSLICES][BINS][NCOLS]   (15.7 MB)
//   blockPart: float[8]
//   ctr  : u32
#define WS_PART  0
#define WS_BPART (YSLICES * BINS * NCOLS * 4)
#define WS_CTR   (WS_BPART + 8 * 4)

// ---------------------------------------------------------------------------
// Kernel A (R8): 20 waves/CU phase decorrelation.
// R7 ablation: loads alone 18.3us, math+LDS alone ~16us, combined 50us at
// 2 waves/SIMD -> neither resource is the wall; heterogeneous stall phases
// (vmcnt vs lgkm/trans) can't cross-cover with only 2 waves/SIMD.
// R8: COLS_PER_BLK 256->64, 4-way row-split inside the block:
//   thread (cl = t&63, g = t>>6) owns column bx*64+cl, rows-group g
//   (rows by*128 + g*32 + [0,32)). H[g][b][cl] exclusive per thread ->
//   still zero atomics / zero hot-loop barriers. LDS stays 30720 B
//   (120 B/thread is this design's invariant), so 160KB/CU -> 5 resident
//   blocks/CU = 20 waves/CU (was 2 blocks via grid shortage), grid 2048.
// Loads: wave = 64 lanes same g -> 64 consecutive dwords = 256 B/row,
// coalesced. H bank = cl%32 -> 2-way, free. Row-groups partition rows ->
// flush-sum per cell = identical integer total -> part[] bit-identical.
// ---------------------------------------------------------------------------
__global__ __launch_bounds__(256, 5) void k_main(
    const float* __restrict__ preds, const int* __restrict__ targets,
    unsigned int* __restrict__ part, unsigned int* __restrict__ ctr)
{
    __shared__ unsigned int H[ROW_SPLIT * BINS * COLS_PER_BLK];  // 30720 B
    const int t = threadIdx.x;
    if (blockIdx.x == 0 && blockIdx.y == 0 && t == 0) atomicExch(ctr, 0u);
    for (int i = t; i < ROW_SPLIT * BINS * COLS_PER_BLK; i += 256) H[i] = 0u;
    __syncthreads();

    const int cl = t & 63;
    const int g  = t >> 6;                       // row-group 0..3
    const int col = blockIdx.x * COLS_PER_BLK + cl;
    const int r0  = blockIdx.y * ROWS_PER_BLK + g * 32;
    const float* P = preds   + (size_t)r0 * NCOLS + col;
    const int*   T = targets + (size_t)r0 * NCOLS + col;
    unsigned int* Hg = &H[g * BINS * COLS_PER_BLK + cl];

    // prologue: batch 0 (8 rows) in flight
    float pc[8]; int tc[8];
    #pragma unroll
    for (int r = 0; r < 8; ++r) { pc[r] = P[r * NCOLS]; tc[r] = T[r * NCOLS]; }

    #pragma unroll 1
    for (int batch = 0; batch < 4; ++batch) {     // 32 rows / 8
        float pn[8]; int tn[8];
        if (batch < 3) {
            P += 8 * NCOLS; T += 8 * NCOLS;
            #pragma unroll
            for (int r = 0; r < 8; ++r) { pn[r] = P[r * NCOLS]; tn[r] = T[r * NCOLS]; }
        }
        __builtin_amdgcn_sched_barrier(0);       // prefetch loads may not sink

        #pragma unroll
        for (int r = 0; r < 8; ++r) {
            float p  = pc[r];
            float pp = tc[r] ? -p : p;                    // p'
            float e  = __expf(-fabsf(pp));                // exp(-|p'|)
            float d  = 1.0f + e;
            float r1 = __builtin_amdgcn_rcpf(d);
            float g_ = (pp >= 0.0f) ? r1 : e * r1;        // sigmoid(p')
            int   b  = (int)(g_ * 30.0f);
            b = b > (BINS - 1) ? (BINS - 1) : b;
            float bce = fmaxf(pp, 0.0f) + __logf(d);      // softplus(p')
            unsigned int pk = (1u << CNT_SHIFT)
                | (unsigned int)(bce * FIXED_SCALE + 0.5f);
            Hg[b * COLS_PER_BLK] += pk;                   // exclusive, plain RMW
        }
        #pragma unroll
        for (int r = 0; r < 8; ++r) { pc[r] = pn[r]; tc[r] = tn[r]; }
    }
    __syncthreads();

    // flush: part[by][b][bx*64+cl] = sum over 4 row-group copies (exact u32)
    const size_t outBase = (size_t)blockIdx.y * CELLS
                         + (size_t)blockIdx.x * COLS_PER_BLK;
    for (int i = t; i < BINS * COLS_PER_BLK; i += 256) {
        const int b = i >> 6;
        const int c = i & 63;
        unsigned int v = H[0 * BINS * COLS_PER_BLK + b * COLS_PER_BLK + c]
                       + H[1 * BINS * COLS_PER_BLK + b * COLS_PER_BLK + c]
                       + H[2 * BINS * COLS_PER_BLK + b * COLS_PER_BLK + c]
                       + H[3 * BINS * COLS_PER_BLK + b * COLS_PER_BLK + c];
        part[outBase + (size_t)b * NCOLS + c] = v;
    }
}

// ---------------------------------------------------------------------------
// Kernel B (R5): parallel y-slice reduction, in-place into part. Unchanged.
// ---------------------------------------------------------------------------
__global__ __launch_bounds__(256) void k_reduce16(
    unsigned int* __restrict__ part)
{
    const int gid   = blockIdx.x * 256 + threadIdx.x;
    const int chunk = gid / CELLS;
    const int cell  = gid % CELLS;
    unsigned int* Pp = part + (size_t)(chunk * 16) * CELLS + cell;

    unsigned int c = 0u, s = 0u;
    #pragma unroll
    for (int y = 0; y < 16; ++y) {
        const unsigned int v = Pp[(size_t)y * CELLS];
        c += v >> CNT_SHIFT;
        s += v & SUM_MASK;
    }
    Pp[0]     = c;
    Pp[CELLS] = s;
}

// ---------------------------------------------------------------------------
// Kernel C (R5): per-column contraction + deterministic finale. Unchanged.
// ---------------------------------------------------------------------------
__global__ __launch_bounds__(256) void k_tail(
    const unsigned int* __restrict__ part,
    const float* __restrict__ acc_sum,
    float* __restrict__ blockPart, unsigned int* __restrict__ ctr,
    float* __restrict__ out)
{
    __shared__ float wave_sums[4];
    const int t = threadIdx.x;
    const int c = blockIdx.x * 256 + t;

    float colsum = 0.0f;
    int n = 0;
    #pragma unroll
    for (int b = 0; b < BINS; ++b) {
        const int cell = b * NCOLS + c;
        unsigned int cu = part[(size_t) 0 * CELLS + cell]
                        + part[(size_t)16 * CELLS + cell]
                        + part[(size_t)32 * CELLS + cell]
                        + part[(size_t)48 * CELLS + cell];
        unsigned int su = part[(size_t) 1 * CELLS + cell]
                        + part[(size_t)17 * CELLS + cell]
                        + part[(size_t)33 * CELLS + cell]
                        + part[(size_t)49 * CELLS + cell];
        const float cnt = (float)cu;
        if (cnt >= 1.0f) {
            n += 1;
            float acc_new = 0.75f * acc_sum[cell] + 0.25f * cnt;
            colsum += ((float)su * (1.0f / FIXED_SCALE)) / acc_new;
        }
    }
    colsum /= (float)((n > 1 ? n : 1) * NCOLS);

    #pragma unroll
    for (int off = 32; off > 0; off >>= 1)
        colsum += __shfl_down(colsum, off, 64);
    if ((t & 63) == 0) wave_sums[t >> 6] = colsum;
    __syncthreads();

    if (t == 0) {
        const float s = wave_sums[0] + wave_sums[1] + wave_sums[2] + wave_sums[3];
        atomicExch(&blockPart[blockIdx.x], s);
        __threadfence();
        if (atomicAdd(ctr, 1u) == 7u) {
            __threadfence();
            double d = 0.0;
            #pragma unroll
            for (int i = 0; i < 8; ++i)
                d += (double)atomicAdd(&blockPart[i], 0.0f);
            out[0] = (float)d;
        }
    }
}

extern "C" void kernel_launch(void* const* d_in, const int* in_sizes, int n_in,
                              void* d_out, int out_size, void* d_ws, size_t ws_size,
                              hipStream_t stream)
{
    const float* preds   = (const float*)d_in[0];
    const int*   targets = (const int*)d_in[1];
    const float* acc_sum = (const float*)d_in[2];

    unsigned int* part = (unsigned int*)((char*)d_ws + WS_PART);
    float* blockPart   = (float*)((char*)d_ws + WS_BPART);
    unsigned int* ctr  = (unsigned int*)((char*)d_ws + WS_CTR);

    dim3 gA(NCOLS / COLS_PER_BLK, NROWS / ROWS_PER_BLK);   // (32, 64) = 2048
    k_main<<<gA, 256, 0, stream>>>(preds, targets, part, ctr);

    k_reduce16<<<(4 * CELLS) / 256, 256, 0, stream>>>(part);

    k_tail<<<NCOLS / 256, 256, 0, stream>>>(part, acc_sum, blockPart, ctr,
                                            (float*)d_out);
}

// Round 9
// 179.454 us; speedup vs baseline: 1.4011x; 1.0272x over previous
//
#include <hip/hip_runtime.h>

#define BINS  30
#define NROWS 8192
#define NCOLS 2048
#define COLS_PER_BLK 256                 // grid.x = 8
#define ROWS_PER_BLK 128                 // grid.y = 64
#define YSLICES 64
#define CELLS   (BINS * NCOLS)           // 61440

#define FIXED_SCALE 16384.0f             // 2^14 fixed point for bce
#define CNT_SHIFT   24                   // count bits [24:31], sum in [0:24)
#define SUM_MASK    ((1u << CNT_SHIFT) - 1)

#define NBUF      3                      // LDS ring depth (tiles in flight)
#define TILE_ROWS 8
#define NTILES    (ROWS_PER_BLK / TILE_ROWS)   // 16

// ws layout (bytes) — unchanged:
//   part : u32[YSLICES][BINS][NCOLS]   (15.7 MB)
//   blockPart: float[8]
//   ctr  : u32
#define WS_PART  0
#define WS_BPART (YSLICES * BINS * NCOLS * 4)
#define WS_CTR   (WS_BPART + 8 * 4)

#define FENCE asm volatile("" ::: "memory")

// async global->LDS, 16B/lane, LDS dest = wave-uniform base + lane*16
__device__ __forceinline__ void gll16(const void* g, void* l)
{
    __builtin_amdgcn_global_load_lds(
        (const __attribute__((address_space(1))) void*)g,
        (__attribute__((address_space(3))) void*)l, 16, 0, 0);
}

// ---------------------------------------------------------------------------
// Kernel A (R9): PRODUCER/CONSUMER WAVE SPECIALIZATION.
// R7/R8 evidence: loads-only 18.3us (7 TB/s delivered), math+LDS-only 16us,
// combined 50-55us INVARIANT across structure and occupancy (16->36% no
// effect). Mechanism: per-wave phase coupling — during the math/RMW phase a
// wave holds ~0 bytes in flight, so chip-wide outstanding-bytes (Little's
// law) collapses delivered BW 7 -> 2.3 TB/s. More waves don't help; every
// wave has the same low outstanding-bytes duty cycle.
// Fix: waves 0-3 = consumers (LDS-read + math + exclusive H RMW, col t),
// waves 4-7 = producers (global_load_lds ONLY, 3-deep ring, counted
// vmcnt(4) so the next tile's loads stay in flight ACROSS the raw
// s_barrier — never drained; __syncthreads would vmcnt(0)-drain, so the
// tile loop uses __builtin_amdgcn_s_barrier + compiler fences instead).
// Ring protocol (tile k in buf k%3): fill T(k+2) in segment k; wait
// T(k+1) complete (vmcnt(4): 4 newest = T(k+2)) before barrier A(k+1);
// eat Tk in segment k. Fill of buf b at k overwrites tile eaten at k-1,
// sequenced by A(k). 2 blocks/CU (78KB LDS), grid 512 = fully resident.
// Math byte-identical to R3 -> part[] bit-identical.
// ---------------------------------------------------------------------------
__global__ __launch_bounds__(512, 4) void k_main(
    const float* __restrict__ preds, const int* __restrict__ targets,
    unsigned int* __restrict__ part, unsigned int* __restrict__ ctr)
{
    __shared__ unsigned int H[BINS * COLS_PER_BLK];                     // 30720 B
    __shared__ __align__(16) float TbP[NBUF][TILE_ROWS][COLS_PER_BLK];  // 24576 B
    __shared__ __align__(16) int   TbT[NBUF][TILE_ROWS][COLS_PER_BLK];  // 24576 B

    const int t    = threadIdx.x;
    const int wv   = t >> 6;
    const int lane = t & 63;
    if (blockIdx.x == 0 && blockIdx.y == 0 && t == 0) atomicExch(ctr, 0u);

    for (int i = t; i < BINS * COLS_PER_BLK; i += 512) H[i] = 0u;
    __syncthreads();                       // H zero visible (nothing in flight)

    const float* Pbase = preds   + (size_t)(blockIdx.y * ROWS_PER_BLK) * NCOLS
                                 + blockIdx.x * COLS_PER_BLK;
    const int*   Tbase = targets + (size_t)(blockIdx.y * ROWS_PER_BLK) * NCOLS
                                 + blockIdx.x * COLS_PER_BLK;

    const bool is_prod = (wv >= 4);
    const int  pw      = wv - 4;           // producer wave 0..3: rows 2pw,2pw+1

    // producer: stage tile k (8 rows x {preds,targets}) into buf k%NBUF
    auto issue = [&](int k) {
        const int b = k % NBUF;
        #pragma unroll
        for (int j = 0; j < 2; ++j) {
            const int lr  = 2 * pw + j;
            const int row = k * TILE_ROWS + lr;
            gll16(Pbase + (size_t)row * NCOLS + 4 * lane, &TbP[b][lr][0]);
            gll16(Tbase + (size_t)row * NCOLS + 4 * lane, &TbT[b][lr][0]);
        }
    };

    if (is_prod) {
        issue(0); issue(1);                              // depth-2 prologue
        asm volatile("s_waitcnt vmcnt(4)" ::: "memory"); // T0 complete
        __builtin_amdgcn_sched_barrier(0);
    }
    FENCE; __builtin_amdgcn_s_barrier(); FENCE;          // A(0)

    #pragma unroll 1
    for (int k = 0; k < NTILES; ++k) {
        if (!is_prod) {
            // consumer: thread t (<256) owns column t — exclusive H RMW
            const int buf = k % NBUF;
            #pragma unroll
            for (int r = 0; r < TILE_ROWS; ++r) {
                float p  = TbP[buf][r][t];
                int   tv = TbT[buf][r][t];
                float pp = tv ? -p : p;                    // p'
                float e  = __expf(-fabsf(pp));             // exp(-|p'|)
                float d  = 1.0f + e;
                float r1 = __builtin_amdgcn_rcpf(d);
                float g  = (pp >= 0.0f) ? r1 : e * r1;     // sigmoid(p')
                int   bi = (int)(g * 30.0f);
                bi = bi > (BINS - 1) ? (BINS - 1) : bi;
                float bce = fmaxf(pp, 0.0f) + __logf(d);   // softplus(p')
                unsigned int pk = (1u << CNT_SHIFT)
                    | (unsigned int)(bce * FIXED_SCALE + 0.5f);
                H[bi * COLS_PER_BLK + t] += pk;            // exclusive RMW
            }
        } else {
            if (k + 2 < NTILES) {
                issue(k + 2);                              // refills buf eaten at k-1
                asm volatile("s_waitcnt vmcnt(4)" ::: "memory");  // T(k+1) done
            } else {
                asm volatile("s_waitcnt vmcnt(0)" ::: "memory");  // drain tail
            }
            __builtin_amdgcn_sched_barrier(0);
        }
        FENCE; __builtin_amdgcn_s_barrier(); FENCE;        // A(k+1)
    }

    __syncthreads();                                       // H stable, all drained

    // flush: straight copy, coalesced, all 512 threads
    const size_t outBase = (size_t)blockIdx.y * CELLS
                         + (size_t)blockIdx.x * COLS_PER_BLK;
    for (int i = t; i < BINS * COLS_PER_BLK; i += 512)
        part[outBase + (size_t)(i >> 8) * NCOLS + (i & 255)] = H[i];
}

// ---------------------------------------------------------------------------
// Kernel B (R5): parallel y-slice reduction, in-place into part. Unchanged.
// ---------------------------------------------------------------------------
__global__ __launch_bounds__(256) void k_reduce16(
    unsigned int* __restrict__ part)
{
    const int gid   = blockIdx.x * 256 + threadIdx.x;
    const int chunk = gid / CELLS;
    const int cell  = gid % CELLS;
    unsigned int* Pp = part + (size_t)(chunk * 16) * CELLS + cell;

    unsigned int c = 0u, s = 0u;
    #pragma unroll
    for (int y = 0; y < 16; ++y) {
        const unsigned int v = Pp[(size_t)y * CELLS];
        c += v >> CNT_SHIFT;
        s += v & SUM_MASK;
    }
    Pp[0]     = c;
    Pp[CELLS] = s;
}

// ---------------------------------------------------------------------------
// Kernel C (R5): per-column contraction + deterministic finale. Unchanged.
// ---------------------------------------------------------------------------
__global__ __launch_bounds__(256) void k_tail(
    const unsigned int* __restrict__ part,
    const float* __restrict__ acc_sum,
    float* __restrict__ blockPart, unsigned int* __restrict__ ctr,
    float* __restrict__ out)
{
    __shared__ float wave_sums[4];
    const int t = threadIdx.x;
    const int c = blockIdx.x * 256 + t;

    float colsum = 0.0f;
    int n = 0;
    #pragma unroll
    for (int b = 0; b < BINS; ++b) {
        const int cell = b * NCOLS + c;
        unsigned int cu = part[(size_t) 0 * CELLS + cell]
                        + part[(size_t)16 * CELLS + cell]
                        + part[(size_t)32 * CELLS + cell]
                        + part[(size_t)48 * CELLS + cell];
        unsigned int su = part[(size_t) 1 * CELLS + cell]
                        + part[(size_t)17 * CELLS + cell]
                        + part[(size_t)33 * CELLS + cell]
                        + part[(size_t)49 * CELLS + cell];
        const float cnt = (float)cu;
        if (cnt >= 1.0f) {
            n += 1;
            float acc_new = 0.75f * acc_sum[cell] + 0.25f * cnt;
            colsum += ((float)su * (1.0f / FIXED_SCALE)) / acc_new;
        }
    }
    colsum /= (float)((n > 1 ? n : 1) * NCOLS);

    #pragma unroll
    for (int off = 32; off > 0; off >>= 1)
        colsum += __shfl_down(colsum, off, 64);
    if ((t & 63) == 0) wave_sums[t >> 6] = colsum;
    __syncthreads();

    if (t == 0) {
        const float s = wave_sums[0] + wave_sums[1] + wave_sums[2] + wave_sums[3];
        atomicExch(&blockPart[blockIdx.x], s);
        __threadfence();
        if (atomicAdd(ctr, 1u) == 7u) {
            __threadfence();
            double d = 0.0;
            #pragma unroll
            for (int i = 0; i < 8; ++i)
                d += (double)atomicAdd(&blockPart[i], 0.0f);
            out[0] = (float)d;
        }
    }
}

extern "C" void kernel_launch(void* const* d_in, const int* in_sizes, int n_in,
                              void* d_out, int out_size, void* d_ws, size_t ws_size,
                              hipStream_t stream)
{
    const float* preds   = (const float*)d_in[0];
    const int*   targets = (const int*)d_in[1];
    const float* acc_sum = (const float*)d_in[2];

    unsigned int* part = (unsigned int*)((char*)d_ws + WS_PART);
    float* blockPart   = (float*)((char*)d_ws + WS_BPART);
    unsigned int* ctr  = (unsigned int*)((char*)d_ws + WS_CTR);

    dim3 gA(NCOLS / COLS_PER_BLK, NROWS / ROWS_PER_BLK);   // (8, 64) = 512 blocks
    k_main<<<gA, 512, 0, stream>>>(preds, targets, part, ctr);

    k_reduce16<<<(4 * CELLS) / 256, 256, 0, stream>>>(part);

    k_tail<<<NCOLS / 256, 256, 0, stream>>>(part, acc_sum, blockPart, ctr,
                                            (float*)d_out);
}